// Round 10
// baseline (466.298 us; speedup 1.0000x reference)
//
#include <hip/hip_runtime.h>

// GCN 2-layer forward on MI355X (gfx950).
// out = A @ relu(A @ (x@W1) + b1) @ W2 + b2   (A = weighted edge aggregation)
// R17: barrier-free gemm1 with LDS-resident W1t.
//  - R16 post-mortem: more waves, MORE barriers -> slower (75us). The per-phase
//    __syncthreads drain (compiler emits vmcnt(0) before s_barrier) is the
//    binding constraint, not outstanding-bytes.
//  - W1t (128KB) fits in LDS whole (133KB padded). New gemm1h: 256 blocks x
//    1024 thr (1 block/CU, 16 waves), stage W1t ONCE (single barrier), then
//    each wave runs one 16x128 tile as straight-line code: 16 ksteps, 32
//    independent X float4 loads, 128 MFMAs, zero barriers -> compiler can
//    pipeline loads across ksteps.
//  - Tiles interleaved (tile = bid + 256*wv) so all blocks have ~13 busy waves.
//  - hist atomics (4/thread) issue after the barrier, land under MFMA region.
//  - scan_fused / scatter / agg1 / gemm2 / agg2 verbatim R15 (best: 295us).

#define F0 512
#define F1 128
#define F2 40
#define F2P 48   // padded S2 row (bf16)
#define G1_GRID 256
#define SBPAD 520   // 512+8 shorts: read stride 260 words -> 2-way bank alias (free)

typedef short bf16x8 __attribute__((ext_vector_type(8)));
typedef float f32x4 __attribute__((ext_vector_type(4)));

// accurate RNE bf16 (weights, once per call)
static __device__ __forceinline__ unsigned short f2b(float f){
    union { float f; unsigned int u; } x; x.f = f;
    unsigned int u = x.u;
    unsigned int r = (u + 0x7fffu + ((u >> 16) & 1u)) >> 16;
    return (unsigned short)r;
}
// fast round-half-up bf16 (activations)
static __device__ __forceinline__ unsigned short f2b_fast(float f){
    return (unsigned short)((__float_as_uint(f) + 0x8000u) >> 16);
}
static __device__ __forceinline__ unsigned int pack2(float a, float b){
    unsigned int ua = __float_as_uint(a) + 0x8000u;
    unsigned int ub = __float_as_uint(b) + 0x8000u;
    return __builtin_amdgcn_perm(ub, ua, 0x07060302u);
}
static __device__ __forceinline__ bf16x8 pack8(float4 v0, float4 v1){
    union { bf16x8 v; unsigned int d[4]; } r;
    r.d[0] = pack2(v0.x, v0.y);
    r.d[1] = pack2(v0.z, v0.w);
    r.d[2] = pack2(v1.x, v1.y);
    r.d[3] = pack2(v1.z, v1.w);
    return r.v;
}
static __device__ __forceinline__ float b2f(unsigned short h){
    union { unsigned int u; float f; } x; x.u = ((unsigned int)h) << 16; return x.f;
}
// fp16 pack/unpack for edge weights (w in [0,1): rel err 2^-11)
static __device__ __forceinline__ unsigned short f2h(float f){
    union { _Float16 h; unsigned short u; } x; x.h = (_Float16)f; return x.u;
}
static __device__ __forceinline__ float h2f(unsigned short u){
    union { unsigned short u; _Float16 h; } x; x.u = u; return (float)x.h;
}

// ---------------- weight prep + cnt8/gflag zero (fused) ----------------
__global__ void prep_w(const float* __restrict__ W1, const float* __restrict__ W2,
                       unsigned short* __restrict__ W1t, unsigned short* __restrict__ W2t,
                       int* __restrict__ cnt8, int n8, int* __restrict__ gflag){
    int idx = blockIdx.x*256 + threadIdx.x;   // grid covers max(400000, 71680)
    if (idx < n8) cnt8[idx] = 0;
    if (idx < 64) gflag[idx] = 0;             // scan cross-block flags
    if (idx < F0*F1){                    // W1 [512][128] -> W1t [128][512]
        int k = idx >> 7, n = idx & 127;
        W1t[(size_t)n*F0 + k] = f2b(W1[idx]);
    } else if (idx < F0*F1 + F2P*F1){    // W2 [128][40] -> W2t [48][128]
        int j = idx - F0*F1;
        int n = j >> 7, k = j & 127;
        float v = (n < F2) ? W2[(size_t)k*F2 + n] : 0.f;
        W2t[j] = f2b(v);
    }
}

// ---- GEMM1 (LDS-resident W1t, barrier-free main loop) + overlapped hist ----
// X[M,512]fp32 @ W1t -> S1 bf16 [M,128]. 1024 thr = 16 waves; wave wv handles
// tile = bid + 256*wv (16 rows x 128 cols, straight-line 16 ksteps).
__global__ __launch_bounds__(1024, 1) void gemm1h(const float* __restrict__ X,
                                                  const unsigned short* __restrict__ W1t,
                                                  unsigned short* __restrict__ S1, int M,
                                                  const int* __restrict__ dst,
                                                  int* __restrict__ cnt8,
                                                  unsigned short* __restrict__ slot,
                                                  int E, int epb){
    __shared__ unsigned short sB[128*SBPAD];   // 133 KB: full W1t, padded
    int tid = threadIdx.x;
    int wv = tid >> 6, lane = tid & 63;
    int quad = lane >> 4, l16 = lane & 15;
    int nt = (M + 15) >> 4;                    // 16-row tiles (3125)

    // stage all of W1t: 8192 float4 across 1024 threads (8 each)
    #pragma unroll
    for (int i=0;i<8;i++){
        int idx = tid + i*1024;                // 0..8191
        int nn = idx >> 6, c8 = idx & 63;
        *(float4*)&sB[nn*SBPAD + c8*8] = *(const float4*)&W1t[(size_t)nn*F0 + c8*8];
    }
    __syncthreads();                           // the ONLY barrier

    // hist: 4 edges/thread, atomics issued now, results consumed at the end
    int ebase = blockIdx.x * epb;
    int eend  = min(ebase + epb, E);
    int e0 = ebase + tid, e1 = e0 + 1024, e2 = e0 + 2048, e3 = e0 + 3072;
    unsigned int s0v=0, s1v=0, s2v=0, s3v=0;
    if (e0 < eend) s0v = atomicAdd(&cnt8[dst[e0]*8 + (e0 & 7)], 1);
    if (e1 < eend) s1v = atomicAdd(&cnt8[dst[e1]*8 + (e1 & 7)], 1);
    if (e2 < eend) s2v = atomicAdd(&cnt8[dst[e2]*8 + (e2 & 7)], 1);
    if (e3 < eend) s3v = atomicAdd(&cnt8[dst[e3]*8 + (e3 & 7)], 1);

    // MFMA tiles: straight-line, no barriers (compiler pipelines X loads)
    for (int tile = blockIdx.x + G1_GRID*wv; tile < nt; tile += G1_GRID*16){
        int arow = min(tile*16 + l16, M-1);
        const float* xrow = X + (size_t)arow * F0;
        f32x4 acc[8];
        #pragma unroll
        for (int c=0;c<8;c++) acc[c] = (f32x4){0.f,0.f,0.f,0.f};
        #pragma unroll
        for (int s=0;s<16;s++){
            const float* xr = xrow + s*32 + quad*8;
            float4 v0 = *(const float4*)(xr);
            float4 v1 = *(const float4*)(xr + 4);
            bf16x8 af = pack8(v0, v1);
            #pragma unroll
            for (int c=0;c<8;c++){
                bf16x8 b = *(bf16x8*)&sB[(c*16 + l16)*SBPAD + s*32 + quad*8];
                acc[c] = __builtin_amdgcn_mfma_f32_16x16x32_bf16(af, b, acc[c], 0, 0, 0);
            }
        }
        // C/D: col = c*16 + l16, row = quad*4 + r  (verbatim R15 mapping)
        #pragma unroll
        for (int c=0;c<8;c++){
            #pragma unroll
            for (int r=0;r<4;r++){
                int grow = tile*16 + quad*4 + r;
                if (grow < M) S1[(size_t)grow*F1 + c*16 + l16] = f2b_fast(acc[c][r]);
            }
        }
    }

    // slot stores (atomic results long since landed)
    if (e0 < eend) slot[e0] = (unsigned short)s0v;
    if (e1 < eend) slot[e1] = (unsigned short)s1v;
    if (e2 < eend) slot[e2] = (unsigned short)s2v;
    if (e3 < eend) slot[e3] = (unsigned short)s3v;
    // safety: residual edges if epb ever exceeds 4096
    for (int e = ebase + tid + 4096; e < eend; e += 1024){
        slot[e] = (unsigned short)atomicAdd(&cnt8[dst[e]*8 + (e & 7)], 1);
    }
}

// ---------------- fused scan: per-chunk scan + cross-block prefix ----------------
// 49 blocks (1024 nodes each), all co-resident -> flag-spin is deadlock-free.
__global__ void scan_fused(const int* __restrict__ cnt8, int* __restrict__ offs,
                           int* __restrict__ sbase, int* __restrict__ gflag,
                           int n, int E){
    __shared__ int sd[256];
    __shared__ int s_excl;
    int tid = threadIdx.x, bid = blockIdx.x;
    int base = bid*1024 + tid*4;

    int t[4];
    int lpr[4][8];
    #pragma unroll
    for (int j=0;j<4;j++){
        int node = base+j;
        int tot = 0;
        #pragma unroll
        for (int k=0;k<8;k++) lpr[j][k] = 0;
        if (node < n){
            int4 c0 = *(const int4*)&cnt8[(size_t)node*8];
            int4 c1 = *(const int4*)&cnt8[(size_t)node*8+4];
            int run;
            lpr[j][0] = 0;   run  = c0.x;
            lpr[j][1] = run; run += c0.y;
            lpr[j][2] = run; run += c0.z;
            lpr[j][3] = run; run += c0.w;
            lpr[j][4] = run; run += c1.x;
            lpr[j][5] = run; run += c1.y;
            lpr[j][6] = run; run += c1.z;
            lpr[j][7] = run; run += c1.w;
            tot = run;
        }
        t[j] = tot;
    }
    int v1 = t[0], v2 = t[0]+t[1], v3 = v2+t[2];
    int s = v3 + t[3];
    sd[tid] = s; __syncthreads();
    for (int off=1; off<256; off<<=1){
        int tt = (tid>=off) ? sd[tid-off] : 0;
        __syncthreads();
        sd[tid] += tt;
        __syncthreads();
    }
    int excl = sd[tid] - s;
    int btot = sd[255];

    // publish this block's total (value+1 so 0 == not-ready)
    if (tid == 0)
        __hip_atomic_store(&gflag[bid], btot + 1, __ATOMIC_RELEASE, __HIP_MEMORY_SCOPE_AGENT);
    // wave 0: gather predecessors' totals (bid <= 48 < 64 lanes)
    if (tid < 64){
        int v = 0;
        if (tid < bid){
            int g;
            do {
                g = __hip_atomic_load(&gflag[tid], __ATOMIC_ACQUIRE, __HIP_MEMORY_SCOPE_AGENT);
                if (g == 0) __builtin_amdgcn_s_sleep(1);
            } while (g == 0);
            v = g - 1;
        }
        #pragma unroll
        for (int o=1; o<64; o<<=1) v += __shfl_xor(v, o);
        if (tid == 0) s_excl = v;
    }
    __syncthreads();

    int node_off[4] = {0, v1, v2, v3};
    int gexcl = s_excl + excl;
    #pragma unroll
    for (int j=0;j<4;j++){
        int node = base+j;
        if (node < n){
            int o = gexcl + node_off[j];
            offs[node] = o;
            int4 s0, s1;
            s0.x = o + lpr[j][0]; s0.y = o + lpr[j][1];
            s0.z = o + lpr[j][2]; s0.w = o + lpr[j][3];
            s1.x = o + lpr[j][4]; s1.y = o + lpr[j][5];
            s1.z = o + lpr[j][6]; s1.w = o + lpr[j][7];
            *(int4*)&sbase[(size_t)node*8]   = s0;
            *(int4*)&sbase[(size_t)node*8+4] = s1;
        }
    }
    if (bid == 0 && tid == 0) offs[n] = E;
}

// atomic-free scatter: pos = sbase[d][shard] + saved slot
__global__ void scatter_kernel(const int* __restrict__ src, const int* __restrict__ dst,
                               const float* __restrict__ w,
                               const int* __restrict__ sbase,
                               const unsigned short* __restrict__ slot,
                               unsigned int* __restrict__ edges, int E){
    int e = blockIdx.x*256+threadIdx.x;
    if (e<E){
        int d = dst[e];
        int pos = sbase[d*8 + (e & 7)] + (int)slot[e];
        edges[pos] = ((unsigned int)src[e] << 16) | (unsigned int)f2h(w[e]);
    }
}

// ---- agg1: H = relu(A@S1 + b1) bf16, F=128 (unchanged) ----
__global__ void agg1_kernel(const unsigned short* __restrict__ S1, const int* __restrict__ offs,
                            const unsigned int* __restrict__ edges,
                            const float* __restrict__ b1, unsigned short* __restrict__ H, int n){
    int node = blockIdx.x*4 + (threadIdx.x >> 6);   // one wave per node
    int lane = threadIdx.x & 63;
    if (node >= n) return;
    int half = lane >> 5, fl = lane & 31;
    int e0 = offs[node], e1 = offs[node+1];
    double a0=0.0, a1=0.0, a2=0.0, a3=0.0;
    int e = e0;
    for (; e+8 <= e1; e += 8){
        unsigned int rA = edges[e   + half];
        unsigned int rB = edges[e+2 + half];
        unsigned int rC = edges[e+4 + half];
        unsigned int rD = edges[e+6 + half];
        ushort4 vA = *(const ushort4*)&S1[((size_t)(rA>>16))*F1 + fl*4];
        ushort4 vB = *(const ushort4*)&S1[((size_t)(rB>>16))*F1 + fl*4];
        ushort4 vC = *(const ushort4*)&S1[((size_t)(rC>>16))*F1 + fl*4];
        ushort4 vD = *(const ushort4*)&S1[((size_t)(rD>>16))*F1 + fl*4];
        double wA = h2f((unsigned short)rA), wB = h2f((unsigned short)rB);
        double wC = h2f((unsigned short)rC), wD = h2f((unsigned short)rD);
        a0 += wA*b2f(vA.x) + wB*b2f(vB.x) + wC*b2f(vC.x) + wD*b2f(vD.x);
        a1 += wA*b2f(vA.y) + wB*b2f(vB.y) + wC*b2f(vC.y) + wD*b2f(vD.y);
        a2 += wA*b2f(vA.z) + wB*b2f(vB.z) + wC*b2f(vC.z) + wD*b2f(vD.z);
        a3 += wA*b2f(vA.w) + wB*b2f(vB.w) + wC*b2f(vC.w) + wD*b2f(vD.w);
    }
    for (; e < e1; e += 2){
        int ee = e + half;
        if (ee < e1){
            unsigned int r = edges[ee];
            ushort4 v = *(const ushort4*)&S1[((size_t)(r>>16))*F1 + fl*4];
            double w = h2f((unsigned short)r);
            a0 += w*b2f(v.x); a1 += w*b2f(v.y); a2 += w*b2f(v.z); a3 += w*b2f(v.w);
        }
    }
    a0 += __shfl_down(a0, 32);
    a1 += __shfl_down(a1, 32);
    a2 += __shfl_down(a2, 32);
    a3 += __shfl_down(a3, 32);
    if (lane < 32){
        float4 bb = *(const float4*)&b1[fl*4];
        float o0 = (float)(a0 + (double)bb.x);
        float o1 = (float)(a1 + (double)bb.y);
        float o2 = (float)(a2 + (double)bb.z);
        float o3 = (float)(a3 + (double)bb.w);
        o0 = o0>0.f?o0:0.f; o1 = o1>0.f?o1:0.f;
        o2 = o2>0.f?o2:0.f; o3 = o3>0.f?o3:0.f;
        union { ushort4 v; unsigned int d[2]; } o;
        o.d[0] = pack2(o0, o1);
        o.d[1] = pack2(o2, o3);
        *(ushort4*)&H[(size_t)node*F1 + fl*4] = o.v;
    }
}

// ---- GEMM2: H bf16 [M,128] @ W2t -> S2 bf16 [M,48] (unchanged) ----
__global__ __launch_bounds__(256) void gemm2_mfma(const unsigned short* __restrict__ H,
                                                  const unsigned short* __restrict__ W2t,
                                                  unsigned short* __restrict__ S2, int M){
    __shared__ unsigned short sB[48][136];
    int tid = threadIdx.x;
    int wave = tid >> 6, lane = tid & 63;
    int quad = lane >> 4, l16 = lane & 15;
    for (int i = tid; i < 48*16; i += 256){
        int nn = i >> 4, p = i & 15;
        *(float4*)&sB[nn][p*8] = *(const float4*)&W2t[(size_t)nn*F1 + p*8];
    }
    int row0 = blockIdx.x * 64;
    int myrow = row0 + wave*16 + l16;
    int arow = min(myrow, M-1);
    const unsigned short* hrow = H + (size_t)arow * F1;
    bf16x8 a[4];
    #pragma unroll
    for (int ks=0; ks<4; ks++) a[ks] = *(const bf16x8*)(hrow + ks*32 + quad*8);
    __syncthreads();
    f32x4 acc[3];
    #pragma unroll
    for (int c=0;c<3;c++) acc[c] = (f32x4){0.f,0.f,0.f,0.f};
    #pragma unroll
    for (int ks=0; ks<4; ks++){
        #pragma unroll
        for (int c=0;c<3;c++){
            bf16x8 b = *(bf16x8*)&sB[c*16 + l16][ks*32 + quad*8];
            acc[c] = __builtin_amdgcn_mfma_f32_16x16x32_bf16(a[ks], b, acc[c], 0, 0, 0);
        }
    }
    #pragma unroll
    for (int c=0;c<3;c++){
        #pragma unroll
        for (int r=0;r<4;r++){
            int grow = row0 + wave*16 + quad*4 + r;
            if (grow < M) S2[(size_t)grow*F2P + c*16 + l16] = f2b_fast(acc[c][r]);
        }
    }
}

// ---- agg2: out = A@S2 + b2, F=40 (unchanged) ----
__global__ void agg2_kernel(const unsigned short* __restrict__ S2, const int* __restrict__ offs,
                            const unsigned int* __restrict__ edges,
                            const float* __restrict__ b2, float* __restrict__ out, int n){
    int node = blockIdx.x*4 + (threadIdx.x >> 6);  // one wave per node
    int lane = threadIdx.x & 63;
    if (node >= n) return;
    int grp = lane >> 4, gl = lane & 15;
    bool act = gl < 10;
    int e0 = offs[node], e1 = offs[node+1];
    double a0=0.0, a1=0.0, a2=0.0, a3=0.0;
    for (int e = e0; e < e1; e += 4){
        int ee = e + grp;
        if (ee < e1 && act){
            unsigned int r = edges[ee];
            ushort4 v = *(const ushort4*)&S2[((size_t)(r>>16))*F2P + gl*4];
            double w = h2f((unsigned short)r);
            a0 += w*b2f(v.x); a1 += w*b2f(v.y); a2 += w*b2f(v.z); a3 += w*b2f(v.w);
        }
    }
    a0 += __shfl_down(a0, 32); a0 += __shfl_down(a0, 16);
    a1 += __shfl_down(a1, 32); a1 += __shfl_down(a1, 16);
    a2 += __shfl_down(a2, 32); a2 += __shfl_down(a2, 16);
    a3 += __shfl_down(a3, 32); a3 += __shfl_down(a3, 16);
    if (lane < 10){
        float4 bb = *(const float4*)&b2[lane*4];
        float4 o;
        o.x = (float)(a0 + (double)bb.x);
        o.y = (float)(a1 + (double)bb.y);
        o.z = (float)(a2 + (double)bb.z);
        o.w = (float)(a3 + (double)bb.w);
        *(float4*)&out[(size_t)node*F2 + lane*4] = o;
    }
}

extern "C" void kernel_launch(void* const* d_in, const int* in_sizes, int n_in,
                              void* d_out, int out_size, void* d_ws, size_t ws_size,
                              hipStream_t stream){
    const float* x    = (const float*)d_in[0];
    const int*   esrc = (const int*)d_in[1];
    const int*   edst = (const int*)d_in[2];
    const float* ew   = (const float*)d_in[3];
    const float* W1   = (const float*)d_in[4];
    const float* b1   = (const float*)d_in[5];
    const float* W2   = (const float*)d_in[6];
    const float* b2   = (const float*)d_in[7];
    float* out = (float*)d_out;
    int N = in_sizes[0] / F0;   // 50000
    int E = in_sizes[1];        // 800000

    char* ws = (char*)d_ws;
    size_t off = 0;
    auto alloc = [&](size_t bytes)->void*{
        void* p = ws + off; off += (bytes + 255) & ~(size_t)255; return p;
    };
    unsigned short* S1 = (unsigned short*)alloc(sizeof(unsigned short)*(size_t)N*F1);  // 12.8 MB
    unsigned short* H  = (unsigned short*)alloc(sizeof(unsigned short)*(size_t)N*F1);  // 12.8 MB
    unsigned short* S2 = (unsigned short*)alloc(sizeof(unsigned short)*(size_t)N*F2P); // 4.8 MB
    unsigned short* W1t = (unsigned short*)alloc(sizeof(unsigned short)*F1*F0);
    unsigned short* W2t = (unsigned short*)alloc(sizeof(unsigned short)*F2P*F1);
    int*   offs  = (int*)alloc(sizeof(int)*(size_t)(N+1));
    int*   cnt8  = (int*)alloc(sizeof(int)*(size_t)N*8);                 // 1.6 MB
    int*   sbase = (int*)alloc(sizeof(int)*(size_t)N*8);                 // 1.6 MB
    unsigned short* slot = (unsigned short*)alloc(sizeof(unsigned short)*(size_t)E);   // 1.6 MB
    unsigned int* edges = (unsigned int*)alloc(sizeof(unsigned int)*(size_t)E);        // 3.2 MB
    int*   gflag = (int*)alloc(sizeof(int)*64);

    int n8 = N*8;
    // weight prep + cnt8/gflag zero (grid covers both workloads)
    int prep_items = n8 > (F0*F1 + F2P*F1) ? n8 : (F0*F1 + F2P*F1);
    prep_w<<<(prep_items+255)/256,256,0,stream>>>(W1, W2, W1t, W2t, cnt8, n8, gflag);

    int epb = (E + G1_GRID - 1) / G1_GRID;   // 3125 edges per block
    // GEMM1 (LDS-resident W1t, barrier-free) + overlapped hist
    gemm1h<<<G1_GRID,1024,0,stream>>>(x, W1t, S1, N, edst, cnt8, slot, E, epb);

    // fused scan: per-chunk + cross-block prefix + shard bases (49 blocks)
    int nb = (N+1023)/1024;       // 49 <= 64 (lookback assumes this)
    scan_fused<<<nb,256,0,stream>>>(cnt8, offs, sbase, gflag, N, E);
    scatter_kernel<<<(E+255)/256,256,0,stream>>>(esrc, edst, ew, sbase, slot, edges, E);

    // layer 1 aggregation, layer 2
    agg1_kernel<<<(N+3)/4,256,0,stream>>>(S1, offs, edges, b1, H, N);
    int gemm2_nb = (N+63)/64;     // 782
    gemm2_mfma<<<gemm2_nb,256,0,stream>>>(H, W2t, S2, N);
    agg2_kernel<<<(N+3)/4,256,0,stream>>>(S2, offs, edges, b2, out, N);
}

// Round 12
// 285.705 us; speedup vs baseline: 1.6321x; 1.6321x over previous
//
#include <hip/hip_runtime.h>

// GCN 2-layer forward on MI355X (gfx950).
// out = A @ relu(A @ (x@W1) + b1) @ W2 + b2   (A = weighted edge aggregation)
// R19: resubmit of R18 (container failed twice = infra flake; code audited,
// no hang modes: no new spins, no cooperative launch, loops bounded).
//  - gemm1h + CSR + gemm2 byte-identical R15 (best 295us).
//  - agg1: fp64->fp32 accum (2x VALU, fewer conversions), 16-edge unroll
//    (8 gathers in flight/lane, 2x MLP).
//  - agg2: fp32 accum, 2 edges/group per iter (2x ILP), act widened 10->12
//    lanes (reads S2 zero-padding; exact).
//  - Attribution basis: total - gemm1h = 228+-3us across R14-R17; scan+
//    scatter+prep+gemm2 ~40us, gaps ~25us => aggs ~150-165us.

#define F0 512
#define F1 128
#define F2 40
#define F2P 48   // padded S2 row (bf16)

typedef short bf16x8 __attribute__((ext_vector_type(8)));
typedef float f32x4 __attribute__((ext_vector_type(4)));

// accurate RNE bf16 (weights, once per call)
static __device__ __forceinline__ unsigned short f2b(float f){
    union { float f; unsigned int u; } x; x.f = f;
    unsigned int u = x.u;
    unsigned int r = (u + 0x7fffu + ((u >> 16) & 1u)) >> 16;
    return (unsigned short)r;
}
// fast round-half-up bf16 (activations)
static __device__ __forceinline__ unsigned short f2b_fast(float f){
    return (unsigned short)((__float_as_uint(f) + 0x8000u) >> 16);
}
static __device__ __forceinline__ unsigned int pack2(float a, float b){
    unsigned int ua = __float_as_uint(a) + 0x8000u;
    unsigned int ub = __float_as_uint(b) + 0x8000u;
    return __builtin_amdgcn_perm(ub, ua, 0x07060302u);
}
static __device__ __forceinline__ bf16x8 pack8(float4 v0, float4 v1){
    union { bf16x8 v; unsigned int d[4]; } r;
    r.d[0] = pack2(v0.x, v0.y);
    r.d[1] = pack2(v0.z, v0.w);
    r.d[2] = pack2(v1.x, v1.y);
    r.d[3] = pack2(v1.z, v1.w);
    return r.v;
}
static __device__ __forceinline__ float b2f(unsigned short h){
    union { unsigned int u; float f; } x; x.u = ((unsigned int)h) << 16; return x.f;
}
// fp16 pack/unpack for edge weights (w in [0,1): rel err 2^-11)
static __device__ __forceinline__ unsigned short f2h(float f){
    union { _Float16 h; unsigned short u; } x; x.h = (_Float16)f; return x.u;
}
static __device__ __forceinline__ float h2f(unsigned short u){
    union { unsigned short u; _Float16 h; } x; x.u = u; return (float)x.h;
}

// ---------------- weight prep + cnt8/gflag zero (fused) ----------------
__global__ void prep_w(const float* __restrict__ W1, const float* __restrict__ W2,
                       unsigned short* __restrict__ W1t, unsigned short* __restrict__ W2t,
                       int* __restrict__ cnt8, int n8, int* __restrict__ gflag){
    int idx = blockIdx.x*256 + threadIdx.x;   // grid covers max(400000, 71680)
    if (idx < n8) cnt8[idx] = 0;
    if (idx < 64) gflag[idx] = 0;             // scan cross-block flags
    if (idx < F0*F1){                    // W1 [512][128] -> W1t [128][512]
        int k = idx >> 7, n = idx & 127;
        W1t[(size_t)n*F0 + k] = f2b(W1[idx]);
    } else if (idx < F0*F1 + F2P*F1){    // W2 [128][40] -> W2t [48][128]
        int j = idx - F0*F1;
        int n = j >> 7, k = j & 127;
        float v = (n < F2) ? W2[(size_t)k*F2 + n] : 0.f;
        W2t[j] = f2b(v);
    }
}

// ---- GEMM1 with hist software-pipelined into phases (verbatim R15) ----
__global__ __launch_bounds__(256, 3) void gemm1h(const float* __restrict__ X,
                                                 const unsigned short* __restrict__ W1t,
                                                 unsigned short* __restrict__ S1, int M,
                                                 const int* __restrict__ dst,
                                                 int* __restrict__ cnt8,
                                                 unsigned short* __restrict__ slot,
                                                 int E, int epb){
    __shared__ unsigned short sB[128*136];  // [n][136]: 272B stride -> 2-way alias (free)
    int tid = threadIdx.x;
    int wave = tid >> 6, lane = tid & 63;
    int quad = lane >> 4, l16 = lane & 15;
    int row0 = blockIdx.x * 64;
    int arow = min(row0 + wave*16 + l16, M-1);
    const float* xrow = X + (size_t)arow * F0;

    // this block's hist edges: eb + k*256, k=0..3 (epb == 1024 at N=50K,E=800K)
    int eb = blockIdx.x * epb + tid;
    int e0 = eb, e1 = eb+256, e2 = eb+512, e3 = eb+768;
    int d0 = (e0 < E) ? dst[e0] : 0;
    int d1 = (e1 < E) ? dst[e1] : 0;
    int d2 = (e2 < E) ? dst[e2] : 0;
    int d3 = (e3 < E) ? dst[e3] : 0;
    unsigned int sl = 0;

    f32x4 acc[8];
    #pragma unroll
    for (int c=0;c<8;c++) acc[c] = (f32x4){0.f,0.f,0.f,0.f};

    auto stage_b = [&](int p) __attribute__((always_inline)) {
        __syncthreads();   // prior phase's LDS reads done
        #pragma unroll
        for (int i=0;i<8;i++){
            int idx = tid + i*256;          // 0..2047
            int nn = idx >> 4, c8 = idx & 15;
            *(float4*)&sB[nn*136 + c8*8] =
                *(const float4*)&W1t[(size_t)nn*F0 + p*128 + c8*8];
        }
        __syncthreads();
    };
    auto mfma_ph = [&](int p) __attribute__((always_inline)) {
        #pragma unroll
        for (int s=0;s<4;s++){
            const float* xr = xrow + p*128 + s*32 + quad*8;
            float4 v0 = *(const float4*)(xr);
            float4 v1 = *(const float4*)(xr + 4);
            bf16x8 af = pack8(v0, v1);
            #pragma unroll
            for (int c=0;c<8;c++){
                bf16x8 b = *(bf16x8*)&sB[(c*16 + l16)*136 + s*32 + quad*8];
                acc[c] = __builtin_amdgcn_mfma_f32_16x16x32_bf16(af, b, acc[c], 0, 0, 0);
            }
        }
    };

    stage_b(0);
    if (e0 < E) sl = atomicAdd(&cnt8[d0*8 + (e0 & 7)], 1);   // overlaps phase-0 MFMAs
    mfma_ph(0);

    stage_b(1);
    if (e0 < E) slot[e0] = (unsigned short)sl;               // result ready by now
    if (e1 < E) sl = atomicAdd(&cnt8[d1*8 + (e1 & 7)], 1);
    mfma_ph(1);

    stage_b(2);
    if (e1 < E) slot[e1] = (unsigned short)sl;
    if (e2 < E) sl = atomicAdd(&cnt8[d2*8 + (e2 & 7)], 1);
    mfma_ph(2);

    stage_b(3);
    if (e2 < E) slot[e2] = (unsigned short)sl;
    if (e3 < E) sl = atomicAdd(&cnt8[d3*8 + (e3 & 7)], 1);
    mfma_ph(3);
    if (e3 < E) slot[e3] = (unsigned short)sl;

    // safety: residual edges if epb ever exceeds 1024
    int eend = min(blockIdx.x * epb + epb, E);
    for (int e = eb + 1024; e < eend; e += 256){
        int d = dst[e];
        slot[e] = (unsigned short)atomicAdd(&cnt8[d*8 + (e & 7)], 1);
    }

    // C/D: col = c*16 + l16, row = quad*4 + r
    #pragma unroll
    for (int c=0;c<8;c++){
        #pragma unroll
        for (int r=0;r<4;r++){
            int grow = row0 + wave*16 + quad*4 + r;
            if (grow < M) S1[(size_t)grow*F1 + c*16 + l16] = f2b_fast(acc[c][r]);
        }
    }
}

// ---------------- fused scan: per-chunk scan + cross-block prefix ----------------
__global__ void scan_fused(const int* __restrict__ cnt8, int* __restrict__ offs,
                           int* __restrict__ sbase, int* __restrict__ gflag,
                           int n, int E){
    __shared__ int sd[256];
    __shared__ int s_excl;
    int tid = threadIdx.x, bid = blockIdx.x;
    int base = bid*1024 + tid*4;

    int t[4];
    int lpr[4][8];
    #pragma unroll
    for (int j=0;j<4;j++){
        int node = base+j;
        int tot = 0;
        #pragma unroll
        for (int k=0;k<8;k++) lpr[j][k] = 0;
        if (node < n){
            int4 c0 = *(const int4*)&cnt8[(size_t)node*8];
            int4 c1 = *(const int4*)&cnt8[(size_t)node*8+4];
            int run;
            lpr[j][0] = 0;   run  = c0.x;
            lpr[j][1] = run; run += c0.y;
            lpr[j][2] = run; run += c0.z;
            lpr[j][3] = run; run += c0.w;
            lpr[j][4] = run; run += c1.x;
            lpr[j][5] = run; run += c1.y;
            lpr[j][6] = run; run += c1.z;
            lpr[j][7] = run; run += c1.w;
            tot = run;
        }
        t[j] = tot;
    }
    int v1 = t[0], v2 = t[0]+t[1], v3 = v2+t[2];
    int s = v3 + t[3];
    sd[tid] = s; __syncthreads();
    for (int off=1; off<256; off<<=1){
        int tt = (tid>=off) ? sd[tid-off] : 0;
        __syncthreads();
        sd[tid] += tt;
        __syncthreads();
    }
    int excl = sd[tid] - s;
    int btot = sd[255];

    if (tid == 0)
        __hip_atomic_store(&gflag[bid], btot + 1, __ATOMIC_RELEASE, __HIP_MEMORY_SCOPE_AGENT);
    if (tid < 64){
        int v = 0;
        if (tid < bid){
            int g;
            do {
                g = __hip_atomic_load(&gflag[tid], __ATOMIC_ACQUIRE, __HIP_MEMORY_SCOPE_AGENT);
                if (g == 0) __builtin_amdgcn_s_sleep(1);
            } while (g == 0);
            v = g - 1;
        }
        #pragma unroll
        for (int o=1; o<64; o<<=1) v += __shfl_xor(v, o);
        if (tid == 0) s_excl = v;
    }
    __syncthreads();

    int node_off[4] = {0, v1, v2, v3};
    int gexcl = s_excl + excl;
    #pragma unroll
    for (int j=0;j<4;j++){
        int node = base+j;
        if (node < n){
            int o = gexcl + node_off[j];
            offs[node] = o;
            int4 s0, s1;
            s0.x = o + lpr[j][0]; s0.y = o + lpr[j][1];
            s0.z = o + lpr[j][2]; s0.w = o + lpr[j][3];
            s1.x = o + lpr[j][4]; s1.y = o + lpr[j][5];
            s1.z = o + lpr[j][6]; s1.w = o + lpr[j][7];
            *(int4*)&sbase[(size_t)node*8]   = s0;
            *(int4*)&sbase[(size_t)node*8+4] = s1;
        }
    }
    if (bid == 0 && tid == 0) offs[n] = E;
}

// atomic-free scatter: pos = sbase[d][shard] + saved slot
__global__ void scatter_kernel(const int* __restrict__ src, const int* __restrict__ dst,
                               const float* __restrict__ w,
                               const int* __restrict__ sbase,
                               const unsigned short* __restrict__ slot,
                               unsigned int* __restrict__ edges, int E){
    int e = blockIdx.x*256+threadIdx.x;
    if (e<E){
        int d = dst[e];
        int pos = sbase[d*8 + (e & 7)] + (int)slot[e];
        edges[pos] = ((unsigned int)src[e] << 16) | (unsigned int)f2h(w[e]);
    }
}

// ---- agg1: H = relu(A@S1 + b1) bf16, F=128 ----
// fp32 accumulation + 16-edge unroll (8 concurrent gathers per lane).
__global__ void agg1_kernel(const unsigned short* __restrict__ S1, const int* __restrict__ offs,
                            const unsigned int* __restrict__ edges,
                            const float* __restrict__ b1, unsigned short* __restrict__ H, int n){
    int node = blockIdx.x*4 + (threadIdx.x >> 6);   // one wave per node
    int lane = threadIdx.x & 63;
    if (node >= n) return;
    int half = lane >> 5, fl = lane & 31;
    int e0 = offs[node], e1 = offs[node+1];
    float a0=0.f, a1=0.f, a2=0.f, a3=0.f;
    int e = e0;
    for (; e+16 <= e1; e += 16){
        unsigned int rA = edges[e    + half];
        unsigned int rB = edges[e+2  + half];
        unsigned int rC = edges[e+4  + half];
        unsigned int rD = edges[e+6  + half];
        unsigned int rE = edges[e+8  + half];
        unsigned int rF = edges[e+10 + half];
        unsigned int rG = edges[e+12 + half];
        unsigned int rH = edges[e+14 + half];
        ushort4 vA = *(const ushort4*)&S1[((size_t)(rA>>16))*F1 + fl*4];
        ushort4 vB = *(const ushort4*)&S1[((size_t)(rB>>16))*F1 + fl*4];
        ushort4 vC = *(const ushort4*)&S1[((size_t)(rC>>16))*F1 + fl*4];
        ushort4 vD = *(const ushort4*)&S1[((size_t)(rD>>16))*F1 + fl*4];
        ushort4 vE = *(const ushort4*)&S1[((size_t)(rE>>16))*F1 + fl*4];
        ushort4 vF = *(const ushort4*)&S1[((size_t)(rF>>16))*F1 + fl*4];
        ushort4 vG = *(const ushort4*)&S1[((size_t)(rG>>16))*F1 + fl*4];
        ushort4 vH = *(const ushort4*)&S1[((size_t)(rH>>16))*F1 + fl*4];
        float wA = h2f((unsigned short)rA), wB = h2f((unsigned short)rB);
        float wC = h2f((unsigned short)rC), wD = h2f((unsigned short)rD);
        float wE = h2f((unsigned short)rE), wF = h2f((unsigned short)rF);
        float wG = h2f((unsigned short)rG), wH = h2f((unsigned short)rH);
        a0 += wA*b2f(vA.x) + wB*b2f(vB.x) + wC*b2f(vC.x) + wD*b2f(vD.x)
            + wE*b2f(vE.x) + wF*b2f(vF.x) + wG*b2f(vG.x) + wH*b2f(vH.x);
        a1 += wA*b2f(vA.y) + wB*b2f(vB.y) + wC*b2f(vC.y) + wD*b2f(vD.y)
            + wE*b2f(vE.y) + wF*b2f(vF.y) + wG*b2f(vG.y) + wH*b2f(vH.y);
        a2 += wA*b2f(vA.z) + wB*b2f(vB.z) + wC*b2f(vC.z) + wD*b2f(vD.z)
            + wE*b2f(vE.z) + wF*b2f(vF.z) + wG*b2f(vG.z) + wH*b2f(vH.z);
        a3 += wA*b2f(vA.w) + wB*b2f(vB.w) + wC*b2f(vC.w) + wD*b2f(vD.w)
            + wE*b2f(vE.w) + wF*b2f(vF.w) + wG*b2f(vG.w) + wH*b2f(vH.w);
    }
    for (; e+8 <= e1; e += 8){
        unsigned int rA = edges[e   + half];
        unsigned int rB = edges[e+2 + half];
        unsigned int rC = edges[e+4 + half];
        unsigned int rD = edges[e+6 + half];
        ushort4 vA = *(const ushort4*)&S1[((size_t)(rA>>16))*F1 + fl*4];
        ushort4 vB = *(const ushort4*)&S1[((size_t)(rB>>16))*F1 + fl*4];
        ushort4 vC = *(const ushort4*)&S1[((size_t)(rC>>16))*F1 + fl*4];
        ushort4 vD = *(const ushort4*)&S1[((size_t)(rD>>16))*F1 + fl*4];
        float wA = h2f((unsigned short)rA), wB = h2f((unsigned short)rB);
        float wC = h2f((unsigned short)rC), wD = h2f((unsigned short)rD);
        a0 += wA*b2f(vA.x) + wB*b2f(vB.x) + wC*b2f(vC.x) + wD*b2f(vD.x);
        a1 += wA*b2f(vA.y) + wB*b2f(vB.y) + wC*b2f(vC.y) + wD*b2f(vD.y);
        a2 += wA*b2f(vA.z) + wB*b2f(vB.z) + wC*b2f(vC.z) + wD*b2f(vD.z);
        a3 += wA*b2f(vA.w) + wB*b2f(vB.w) + wC*b2f(vC.w) + wD*b2f(vD.w);
    }
    for (; e < e1; e += 2){
        int ee = e + half;
        if (ee < e1){
            unsigned int r = edges[ee];
            ushort4 v = *(const ushort4*)&S1[((size_t)(r>>16))*F1 + fl*4];
            float w = h2f((unsigned short)r);
            a0 += w*b2f(v.x); a1 += w*b2f(v.y); a2 += w*b2f(v.z); a3 += w*b2f(v.w);
        }
    }
    a0 += __shfl_down(a0, 32);
    a1 += __shfl_down(a1, 32);
    a2 += __shfl_down(a2, 32);
    a3 += __shfl_down(a3, 32);
    if (lane < 32){
        float4 bb = *(const float4*)&b1[fl*4];
        float o0 = a0 + bb.x;
        float o1 = a1 + bb.y;
        float o2 = a2 + bb.z;
        float o3 = a3 + bb.w;
        o0 = o0>0.f?o0:0.f; o1 = o1>0.f?o1:0.f;
        o2 = o2>0.f?o2:0.f; o3 = o3>0.f?o3:0.f;
        union { ushort4 v; unsigned int d[2]; } o;
        o.d[0] = pack2(o0, o1);
        o.d[1] = pack2(o2, o3);
        *(ushort4*)&H[(size_t)node*F1 + fl*4] = o.v;
    }
}

// ---- GEMM2: H bf16 [M,128] @ W2t -> S2 bf16 [M,48] (unchanged) ----
__global__ __launch_bounds__(256) void gemm2_mfma(const unsigned short* __restrict__ H,
                                                  const unsigned short* __restrict__ W2t,
                                                  unsigned short* __restrict__ S2, int M){
    __shared__ unsigned short sB[48][136];
    int tid = threadIdx.x;
    int wave = tid >> 6, lane = tid & 63;
    int quad = lane >> 4, l16 = lane & 15;
    for (int i = tid; i < 48*16; i += 256){
        int nn = i >> 4, p = i & 15;
        *(float4*)&sB[nn][p*8] = *(const float4*)&W2t[(size_t)nn*F1 + p*8];
    }
    int row0 = blockIdx.x * 64;
    int myrow = row0 + wave*16 + l16;
    int arow = min(myrow, M-1);
    const unsigned short* hrow = H + (size_t)arow * F1;
    bf16x8 a[4];
    #pragma unroll
    for (int ks=0; ks<4; ks++) a[ks] = *(const bf16x8*)(hrow + ks*32 + quad*8);
    __syncthreads();
    f32x4 acc[3];
    #pragma unroll
    for (int c=0;c<3;c++) acc[c] = (f32x4){0.f,0.f,0.f,0.f};
    #pragma unroll
    for (int ks=0; ks<4; ks++){
        #pragma unroll
        for (int c=0;c<3;c++){
            bf16x8 b = *(bf16x8*)&sB[c*16 + l16][ks*32 + quad*8];
            acc[c] = __builtin_amdgcn_mfma_f32_16x16x32_bf16(a[ks], b, acc[c], 0, 0, 0);
        }
    }
    #pragma unroll
    for (int c=0;c<3;c++){
        #pragma unroll
        for (int r=0;r<4;r++){
            int grow = row0 + wave*16 + quad*4 + r;
            if (grow < M) S2[(size_t)grow*F2P + c*16 + l16] = f2b_fast(acc[c][r]);
        }
    }
}

// ---- agg2: out = A@S2 + b2, F=40 ----
// fp32 accum, 2 edges/group per iter, act lanes 10->12 (S2 pad = 0).
__global__ void agg2_kernel(const unsigned short* __restrict__ S2, const int* __restrict__ offs,
                            const unsigned int* __restrict__ edges,
                            const float* __restrict__ b2, float* __restrict__ out, int n){
    int node = blockIdx.x*4 + (threadIdx.x >> 6);  // one wave per node
    int lane = threadIdx.x & 63;
    if (node >= n) return;
    int grp = lane >> 4, gl = lane & 15;
    bool act = gl < 12;                            // gl=10,11 read S2 pad (zeros)
    int e0 = offs[node], e1 = offs[node+1];
    float a0=0.f, a1=0.f, a2=0.f, a3=0.f;
    int e = e0;
    for (; e+8 <= e1; e += 8){
        unsigned int rA = edges[e   + grp];
        unsigned int rB = edges[e+4 + grp];
        if (act){
            ushort4 vA = *(const ushort4*)&S2[((size_t)(rA>>16))*F2P + gl*4];
            ushort4 vB = *(const ushort4*)&S2[((size_t)(rB>>16))*F2P + gl*4];
            float wA = h2f((unsigned short)rA), wB = h2f((unsigned short)rB);
            a0 += wA*b2f(vA.x) + wB*b2f(vB.x);
            a1 += wA*b2f(vA.y) + wB*b2f(vB.y);
            a2 += wA*b2f(vA.z) + wB*b2f(vB.z);
            a3 += wA*b2f(vA.w) + wB*b2f(vB.w);
        }
    }
    for (; e < e1; e += 4){
        int ee = e + grp;
        if (ee < e1 && act){
            unsigned int r = edges[ee];
            ushort4 v = *(const ushort4*)&S2[((size_t)(r>>16))*F2P + gl*4];
            float w = h2f((unsigned short)r);
            a0 += w*b2f(v.x); a1 += w*b2f(v.y); a2 += w*b2f(v.z); a3 += w*b2f(v.w);
        }
    }
    a0 += __shfl_down(a0, 32); a0 += __shfl_down(a0, 16);
    a1 += __shfl_down(a1, 32); a1 += __shfl_down(a1, 16);
    a2 += __shfl_down(a2, 32); a2 += __shfl_down(a2, 16);
    a3 += __shfl_down(a3, 32); a3 += __shfl_down(a3, 16);
    if (lane < 10){
        float4 bb = *(const float4*)&b2[lane*4];
        float4 o;
        o.x = a0 + bb.x;
        o.y = a1 + bb.y;
        o.z = a2 + bb.z;
        o.w = a3 + bb.w;
        *(float4*)&out[(size_t)node*F2 + lane*4] = o;
    }
}

extern "C" void kernel_launch(void* const* d_in, const int* in_sizes, int n_in,
                              void* d_out, int out_size, void* d_ws, size_t ws_size,
                              hipStream_t stream){
    const float* x    = (const float*)d_in[0];
    const int*   esrc = (const int*)d_in[1];
    const int*   edst = (const int*)d_in[2];
    const float* ew   = (const float*)d_in[3];
    const float* W1   = (const float*)d_in[4];
    const float* b1   = (const float*)d_in[5];
    const float* W2   = (const float*)d_in[6];
    const float* b2   = (const float*)d_in[7];
    float* out = (float*)d_out;
    int N = in_sizes[0] / F0;   // 50000
    int E = in_sizes[1];        // 800000

    char* ws = (char*)d_ws;
    size_t off = 0;
    auto alloc = [&](size_t bytes)->void*{
        void* p = ws + off; off += (bytes + 255) & ~(size_t)255; return p;
    };
    unsigned short* S1 = (unsigned short*)alloc(sizeof(unsigned short)*(size_t)N*F1);  // 12.8 MB
    unsigned short* H  = (unsigned short*)alloc(sizeof(unsigned short)*(size_t)N*F1);  // 12.8 MB
    unsigned short* S2 = (unsigned short*)alloc(sizeof(unsigned short)*(size_t)N*F2P); // 4.8 MB
    unsigned short* W1t = (unsigned short*)alloc(sizeof(unsigned short)*F1*F0);
    unsigned short* W2t = (unsigned short*)alloc(sizeof(unsigned short)*F2P*F1);
    int*   offs  = (int*)alloc(sizeof(int)*(size_t)(N+1));
    int*   cnt8  = (int*)alloc(sizeof(int)*(size_t)N*8);                 // 1.6 MB
    int*   sbase = (int*)alloc(sizeof(int)*(size_t)N*8);                 // 1.6 MB
    unsigned short* slot = (unsigned short*)alloc(sizeof(unsigned short)*(size_t)E);   // 1.6 MB
    unsigned int* edges = (unsigned int*)alloc(sizeof(unsigned int)*(size_t)E);        // 3.2 MB
    int*   gflag = (int*)alloc(sizeof(int)*64);

    int n8 = N*8;
    // weight prep + cnt8/gflag zero (grid covers both workloads)
    int prep_items = n8 > (F0*F1 + F2P*F1) ? n8 : (F0*F1 + F2P*F1);
    prep_w<<<(prep_items+255)/256,256,0,stream>>>(W1, W2, W1t, W2t, cnt8, n8, gflag);

    int gemm_nb = (N+63)/64;      // 782
    int epb = (E + gemm_nb - 1) / gemm_nb;   // 1024 edges per block
    // GEMM1 with hist pipelined into phases
    gemm1h<<<gemm_nb,256,0,stream>>>(x, W1t, S1, N, edst, cnt8, slot, E, epb);

    // fused scan: per-chunk + cross-block prefix + shard bases (49 blocks)
    int nb = (N+1023)/1024;       // 49 <= 64 (lookback assumes this)
    scan_fused<<<nb,256,0,stream>>>(cnt8, offs, sbase, gflag, N, E);
    scatter_kernel<<<(E+255)/256,256,0,stream>>>(esrc, edst, ew, sbase, slot, edges, E);

    // layer 1 aggregation, layer 2
    agg1_kernel<<<(N+3)/4,256,0,stream>>>(S1, offs, edges, b1, H, N);
    gemm2_mfma<<<gemm_nb,256,0,stream>>>(H, W2t, S2, N);
    agg2_kernel<<<(N+3)/4,256,0,stream>>>(S2, offs, edges, b2, out, N);
}